// Round 5
// baseline (33488.821 us; speedup 1.0000x reference)
//
#include <hip/hip_runtime.h>
#include <math.h>

#define CIN 256
#define K9  2304          // CIN*9
#define TLW 16
#define TLH 8
#define LIS 22            // li row stride (elems); cols 0..17 used

// ---------------------------------------------------------------------------
// Weight reshape/convert kernel: [co][ci*9+r] f32 -> [r][co] (co fastest),
// f64 for cls tower, f32 for reg tower. Runs once per launch (~40MB, ~50us).
// ---------------------------------------------------------------------------
__global__ void cvt_w(const float* __restrict__ cw0, const float* __restrict__ cw1,
                      const float* __restrict__ cw2, const float* __restrict__ cw3,
                      const float* __restrict__ cw4,
                      const float* __restrict__ rw0, const float* __restrict__ rw1,
                      const float* __restrict__ rw2, const float* __restrict__ rw3,
                      const float* __restrict__ rw4,
                      double* __restrict__ W64, double* __restrict__ W64_5,
                      float* __restrict__ W32, float* __restrict__ W32_5)
{
    int idx = blockIdx.x * 256 + threadIdx.x;
    const int N1 = 4 * K9 * 256, N2 = K9 * 720, N3 = 4 * K9 * 256, N4 = K9 * 36;
    if (idx < N1) {
        int l = idx / (K9 * 256); int rem = idx % (K9 * 256);
        int r = rem / 256, co = rem % 256;
        const float* s = l == 0 ? cw0 : l == 1 ? cw1 : l == 2 ? cw2 : cw3;
        W64[idx] = (double)s[(size_t)co * K9 + r];
        return;
    }
    idx -= N1;
    if (idx < N2) {
        int r = idx / 720, co = idx % 720;
        W64_5[idx] = (double)cw4[(size_t)co * K9 + r];
        return;
    }
    idx -= N2;
    if (idx < N3) {
        int l = idx / (K9 * 256); int rem = idx % (K9 * 256);
        int r = rem / 256, co = rem % 256;
        const float* s = l == 0 ? rw0 : l == 1 ? rw1 : l == 2 ? rw2 : rw3;
        W32[idx] = s[(size_t)co * K9 + r];
        return;
    }
    idx -= N3;
    if (idx < N4) {
        int r = idx / 36, co = idx % 36;
        W32_5[idx] = rw4[(size_t)co * K9 + r];
    }
}

// ---------------------------------------------------------------------------
// 3x3 SAME conv, NCHW. Block: 4*CO_W out-channels x (16x8) pixels, 256 thr.
// Wave w owns CO_W channels x all 128 px (2 px per lane). Weights read via
// wave-uniform scalar loads from pre-transposed [r][CO_TOT] tensor -> SGPRs,
// LDS holds only the input tile.
// ---------------------------------------------------------------------------
template<typename TI, typename TA, int CH, int CO_W, bool RELU>
__global__ __launch_bounds__(256, 3) void conv_s(
    const TI* __restrict__ in, const TA* __restrict__ wgtT,
    const float* __restrict__ bias, TA* __restrict__ out,
    int H, int W, int CO_TOT)
{
    const int NCH = CIN / CH;
    const int tilesX = (W + TLW - 1) / TLW;
    const int tx = (blockIdx.x % tilesX) * TLW;
    const int ty = (blockIdx.x / tilesX) * TLH;
    const int b  = blockIdx.y;
    const int tid = threadIdx.x;
    const int w  = __builtin_amdgcn_readfirstlane(tid >> 6);
    const int lane = tid & 63;
    const int row = lane >> 3;          // 0..7
    const int c2  = (lane & 7) * 2;     // 0,2,..,14
    const int co_base = blockIdx.z * (4 * CO_W) + w * CO_W;

    __shared__ __align__(16) TA li[CH * 10 * LIS];

    TA acc[CO_W][2];
    #pragma unroll
    for (int c = 0; c < CO_W; ++c) { acc[c][0] = (TA)0; acc[c][1] = (TA)0; }

    for (int ch = 0; ch < NCH; ++ch) {
        const int ci0 = ch * CH;
        for (int idx = tid; idx < CH * 10 * LIS; idx += 256) {
            int ci = idx / (10 * LIS);
            int rr = idx % (10 * LIS);
            int r = rr / LIS, col = rr % LIS;
            TA v = (TA)0;
            int iy = ty + r - 1, ix = tx + col - 1;
            if (col < TLW + 2 && iy >= 0 && iy < H && ix >= 0 && ix < W)
                v = (TA)in[(((size_t)b * CIN + ci0 + ci) * H + iy) * W + ix];
            li[idx] = v;
        }
        __syncthreads();
        #pragma unroll 4
        for (int ci = 0; ci < CH; ++ci) {
            #pragma unroll
            for (int ky = 0; ky < 3; ++ky) {
                const TA* ip = &li[(ci * 10 + row + ky) * LIS + c2];
                TA ir0 = ip[0], ir1 = ip[1], ir2 = ip[2], ir3 = ip[3];
                #pragma unroll
                for (int kx = 0; kx < 3; ++kx) {
                    const int r = (ci0 + ci) * 9 + ky * 3 + kx;
                    const TA* wp = wgtT + (size_t)r * CO_TOT + co_base;
                    TA x0 = (kx == 0) ? ir0 : (kx == 1) ? ir1 : ir2;
                    TA x1 = (kx == 0) ? ir1 : (kx == 1) ? ir2 : ir3;
                    #pragma unroll
                    for (int c = 0; c < CO_W; ++c) {
                        TA wv = wp[c];
                        acc[c][0] += wv * x0;
                        acc[c][1] += wv * x1;
                    }
                }
            }
        }
        __syncthreads();
    }

    const int oy = ty + row;
    const int ox = tx + c2;
    if (oy < H) {
        #pragma unroll
        for (int c = 0; c < CO_W; ++c) {
            int co = co_base + c;
            TA bv = (TA)bias[co];
            TA v0 = acc[c][0] + bv;
            TA v1 = acc[c][1] + bv;
            if (RELU) { v0 = v0 > (TA)0 ? v0 : (TA)0; v1 = v1 > (TA)0 ? v1 : (TA)0; }
            size_t o = (((size_t)b * CO_TOT + co) * H + oy) * W + ox;
            if (ox + 1 < W) { out[o] = v0; out[o + 1] = v1; }
            else if (ox < W) { out[o] = v0; }
        }
    }
}

// ---------------------------------------------------------------------------
// Final cls conv (256 -> 720, fp64) + fused sigmoid/max/argmax.
// Block: anchor a (80 classes) x (16x8) px; wave w owns 20 classes.
// ---------------------------------------------------------------------------
#define CH5 16
__global__ __launch_bounds__(256, 3) void conv_cls5s(
    const double* __restrict__ in, const double* __restrict__ wgtT, // [2304][720]
    const float* __restrict__ bias, float* __restrict__ scores,
    float* __restrict__ cls_id,
    int H, int W, int level_off, int A_total, int b0)
{
    const int tilesX = (W + TLW - 1) / TLW;
    const int tx = (blockIdx.x % tilesX) * TLW;
    const int ty = (blockIdx.x / tilesX) * TLH;
    const int b  = blockIdx.y;
    const int a  = blockIdx.z;
    const int tid = threadIdx.x;
    const int w  = __builtin_amdgcn_readfirstlane(tid >> 6);
    const int lane = tid & 63;
    const int row = lane >> 3;
    const int c2  = (lane & 7) * 2;
    const int co_loc  = w * 20;          // class within anchor
    const int co_base = a * 80 + co_loc; // column in [2304][720]

    __shared__ __align__(16) double li[CH5 * 10 * LIS];
    __shared__ double redM[4][128];
    __shared__ int    redA[4][128];

    double acc[20][2];
    #pragma unroll
    for (int c = 0; c < 20; ++c) { acc[c][0] = 0.0; acc[c][1] = 0.0; }

    for (int ch = 0; ch < CIN / CH5; ++ch) {
        const int ci0 = ch * CH5;
        for (int idx = tid; idx < CH5 * 10 * LIS; idx += 256) {
            int ci = idx / (10 * LIS);
            int rr = idx % (10 * LIS);
            int r = rr / LIS, col = rr % LIS;
            double v = 0.0;
            int iy = ty + r - 1, ix = tx + col - 1;
            if (col < TLW + 2 && iy >= 0 && iy < H && ix >= 0 && ix < W)
                v = in[(((size_t)b * CIN + ci0 + ci) * H + iy) * W + ix];
            li[idx] = v;
        }
        __syncthreads();
        #pragma unroll 2
        for (int ci = 0; ci < CH5; ++ci) {
            #pragma unroll
            for (int ky = 0; ky < 3; ++ky) {
                const double* ip = &li[(ci * 10 + row + ky) * LIS + c2];
                double ir0 = ip[0], ir1 = ip[1], ir2 = ip[2], ir3 = ip[3];
                #pragma unroll
                for (int kx = 0; kx < 3; ++kx) {
                    const int r = (ci0 + ci) * 9 + ky * 3 + kx;
                    const double* wp = wgtT + (size_t)r * 720 + co_base;
                    double x0 = (kx == 0) ? ir0 : (kx == 1) ? ir1 : ir2;
                    double x1 = (kx == 0) ? ir1 : (kx == 1) ? ir2 : ir3;
                    #pragma unroll
                    for (int c = 0; c < 20; ++c) {
                        double wv = wp[c];
                        acc[c][0] += wv * x0;
                        acc[c][1] += wv * x1;
                    }
                }
            }
        }
        __syncthreads();
    }

    // per-lane argmax over its 20 classes (ascending c -> first-max wins)
    #pragma unroll
    for (int j = 0; j < 2; ++j) {
        double m = acc[0][j] + (double)bias[a * 80 + co_loc];
        int am = co_loc;
        #pragma unroll
        for (int c = 1; c < 20; ++c) {
            double v = acc[c][j] + (double)bias[a * 80 + co_loc + c];
            if (v > m) { m = v; am = co_loc + c; }
        }
        int p = row * 16 + c2 + j;
        redM[w][p] = m;
        redA[w][p] = am;
    }
    __syncthreads();
    if (tid < 128) {
        int p = tid;
        double m = redM[0][p]; int am = redA[0][p];
        #pragma unroll
        for (int t = 1; t < 4; ++t)
            if (redM[t][p] > m) { m = redM[t][p]; am = redA[t][p]; }
        int oy = ty + (p >> 4), ox = tx + (p & 15);
        if (oy < H && ox < W) {
            size_t oi = (size_t)(b0 + b) * A_total + level_off
                      + (size_t)(oy * W + ox) * 9 + a;
            scores[oi] = (float)(1.0 / (1.0 + exp(-m)));
            cls_id[oi] = (float)am;
        }
    }
}

// ---------------------------------------------------------------------------
// Boxes epilogue: analytic anchors + bbox transform from raw reg5 (NCHW, 36ch)
// ---------------------------------------------------------------------------
__global__ void boxes_ep(const float* __restrict__ reg5, float* __restrict__ boxes,
                         int H, int W, int level_off, int A_total, float stride,
                         int b0, int Bc)
{
    int idx = blockIdx.x * 256 + threadIdx.x;
    int total = Bc * H * W * 9;
    if (idx >= total) return;
    int a = idx % 9; int rest = idx / 9;
    int x = rest % W; rest /= W;
    int y = rest % H; int b = rest / H;

    float base = 4.f * stride;
    float scale = exp2f((float)(a % 3) * (1.f / 3.f));
    int ri = a / 3;
    float sr = (ri == 0) ? 0.70710678118654752f : (ri == 1 ? 1.f : 1.41421356237309505f);
    float wa = base * scale / sr;
    float ha = base * scale * sr;
    float cx = (x + 0.5f) * stride, cy = (y + 0.5f) * stride;

    size_t cs = (size_t)H * W;
    const float* rp = reg5 + (((size_t)b * 36 + a * 4) * H + y) * W + x;
    float d0 = rp[0], d1 = rp[cs], d2 = rp[2 * cs], d3 = rp[3 * cs];

    float pcx = cx + d0 * 0.1f * wa;
    float pcy = cy + d1 * 0.1f * ha;
    float pw  = expf(d2 * 0.2f) * wa;
    float ph  = expf(d3 * 0.2f) * ha;

    size_t oi = ((size_t)(b0 + b) * A_total + level_off
               + (size_t)(y * W + x) * 9 + a) * 4;
    boxes[oi + 0] = pcx - 0.5f * pw;
    boxes[oi + 1] = pcy - 0.5f * ph;
    boxes[oi + 2] = pcx + 0.5f * pw;
    boxes[oi + 3] = pcy + 0.5f * ph;
}

// ---------------------------------------------------------------------------
extern "C" void kernel_launch(void* const* d_in, const int* in_sizes, int n_in,
                              void* d_out, int out_size, void* d_ws, size_t ws_size,
                              hipStream_t stream)
{
    const float* feats[5];
    for (int i = 0; i < 5; ++i) feats[i] = (const float*)d_in[i];
    const float* cw[5]; const float* cb[5];
    const float* rw[5]; const float* rb[5];
    for (int i = 0; i < 5; ++i) {
        cw[i] = (const float*)d_in[5 + 2 * i];
        cb[i] = (const float*)d_in[6 + 2 * i];
        rw[i] = (const float*)d_in[15 + 2 * i];
        rb[i] = (const float*)d_in[16 + 2 * i];
    }

    const int A_total = 49104;
    float* scores = (float*)d_out;
    float* cls_id = scores + (size_t)8 * A_total;
    float* boxes  = scores + (size_t)2 * 8 * A_total;

    const int   Hs[5]      = {64, 32, 16, 8, 4};
    const float strides[5] = {8.f, 16.f, 32.f, 64.f, 128.f};
    const int   offs[5]    = {0, 36864, 46080, 48384, 48960};

    // ---- ws layout: transposed weights, then activation ping-pong --------
    const size_t S1 = (size_t)4 * K9 * 256 * 8;   // cls inner f64
    const size_t S2 = (size_t)K9 * 720 * 8;       // cls5 f64
    const size_t S3 = (size_t)4 * K9 * 256 * 4;   // reg inner f32
    const size_t S4 = (size_t)K9 * 36 * 4 + 256;  // reg5 f32 (+ overread pad)
    char* p = (char*)d_ws;
    double* W64   = (double*)p;            p += S1;
    double* W64_5 = (double*)p;            p += S2;
    float*  W32   = (float*)p;             p += S3;
    float*  W32_5 = (float*)p;             p += S4;
    size_t wsW = (size_t)(p - (char*)d_ws);
    wsW = (wsW + 255) & ~(size_t)255;
    char*  actBase  = (char*)d_ws + wsW;
    size_t actBytes = ws_size > wsW ? ws_size - wsW : 0;

    {
        int Ntot = 4 * K9 * 256 + K9 * 720 + 4 * K9 * 256 + K9 * 36;
        cvt_w<<<(Ntot + 255) / 256, 256, 0, stream>>>(
            cw[0], cw[1], cw[2], cw[3], cw[4],
            rw[0], rw[1], rw[2], rw[3], rw[4],
            W64, W64_5, W32, W32_5);
    }

    // ---------------- cls tower (fp64) -------------------------------------
    for (int l = 0; l < 5; ++l) {
        int H = Hs[l], W = Hs[l];
        size_t perb = (size_t)CIN * H * W;
        int Bc = 8;
        while (Bc > 1 && 2ull * Bc * perb * 8 > actBytes) Bc >>= 1;
        double* D0 = (double*)actBase;
        double* D1 = D0 + (size_t)Bc * perb;
        int tiles = ((W + TLW - 1) / TLW) * ((H + TLH - 1) / TLH);
        for (int b0 = 0; b0 < 8; b0 += Bc) {
            dim3 g(tiles, Bc, 4);
            const float* fin = feats[l] + (size_t)b0 * perb;
            conv_s<float,  double, 16, 16, true><<<g, 256, 0, stream>>>(
                fin, W64 + 0 * (size_t)K9 * 256, cb[0], D0, H, W, 256);
            conv_s<double, double, 16, 16, true><<<g, 256, 0, stream>>>(
                D0,  W64 + 1 * (size_t)K9 * 256, cb[1], D1, H, W, 256);
            conv_s<double, double, 16, 16, true><<<g, 256, 0, stream>>>(
                D1,  W64 + 2 * (size_t)K9 * 256, cb[2], D0, H, W, 256);
            conv_s<double, double, 16, 16, true><<<g, 256, 0, stream>>>(
                D0,  W64 + 3 * (size_t)K9 * 256, cb[3], D1, H, W, 256);
            dim3 g5(tiles, Bc, 9);
            conv_cls5s<<<g5, 256, 0, stream>>>(D1, W64_5, cb[4], scores, cls_id,
                                               H, W, offs[l], A_total, b0);
        }
    }

    // ---------------- reg tower (fp32) -------------------------------------
    for (int l = 0; l < 5; ++l) {
        int H = Hs[l], W = Hs[l];
        size_t perb = (size_t)CIN * H * W;
        int Br = 8;
        while (Br > 1 && 2ull * Br * perb * 4 > actBytes) Br >>= 1;
        float* F0 = (float*)actBase;
        float* F1 = F0 + (size_t)Br * perb;
        int tiles = ((W + TLW - 1) / TLW) * ((H + TLH - 1) / TLH);
        for (int b0 = 0; b0 < 8; b0 += Br) {
            dim3 g(tiles, Br, 4);
            const float* fin = feats[l] + (size_t)b0 * perb;
            conv_s<float, float, 16, 16, true><<<g, 256, 0, stream>>>(
                fin, W32 + 0 * (size_t)K9 * 256, rb[0], F0, H, W, 256);
            conv_s<float, float, 16, 16, true><<<g, 256, 0, stream>>>(
                F0,  W32 + 1 * (size_t)K9 * 256, rb[1], F1, H, W, 256);
            conv_s<float, float, 16, 16, true><<<g, 256, 0, stream>>>(
                F1,  W32 + 2 * (size_t)K9 * 256, rb[2], F0, H, W, 256);
            conv_s<float, float, 16, 16, true><<<g, 256, 0, stream>>>(
                F0,  W32 + 3 * (size_t)K9 * 256, rb[3], F1, H, W, 256);
            dim3 gr(tiles, Br, 1);
            conv_s<float, float, 16, 9, false><<<gr, 256, 0, stream>>>(
                F1, W32_5, rb[4], F0, H, W, 36);
            int total = Br * H * W * 9;
            boxes_ep<<<(total + 255) / 256, 256, 0, stream>>>(F0, boxes, H, W,
                                                              offs[l], A_total,
                                                              strides[l], b0, Br);
        }
    }
}

// Round 8
// 25040.047 us; speedup vs baseline: 1.3374x; 1.3374x over previous
//
#include <hip/hip_runtime.h>
#include <math.h>

#define CIN 256
#define K9  2304
#define TLW 16
#define TLH 8
#define LIS 22   // padded li row stride for the vector (round-4) kernels

typedef double f64x4 __attribute__((ext_vector_type(4)));
typedef double f64x2 __attribute__((ext_vector_type(2)));

// ---- f64 MFMA availability probe (module must compile without it) ---------
#if defined(__has_builtin)
#  if __has_builtin(__builtin_amdgcn_mfma_f64_16x16x4f64)
#    define MFMA64(A,B,C) __builtin_amdgcn_mfma_f64_16x16x4f64((A),(B),(C),0,0,0)
#    define HAVE_MFMA64 1
#  elif __has_builtin(__builtin_amdgcn_mfma_f64_16x16x4_f64)
#    define MFMA64(A,B,C) __builtin_amdgcn_mfma_f64_16x16x4_f64((A),(B),(C),0,0,0)
#    define HAVE_MFMA64 1
#  endif
#endif
#ifndef HAVE_MFMA64
#  define HAVE_MFMA64 0
#  define MFMA64(A,B,C) (C)   /* dead code; kernels using it are never launched */
#endif

// ---------------------------------------------------------------------------
// Weight reshape/convert for the MFMA path: [co][r] f32 -> [r][co] f64.
// ---------------------------------------------------------------------------
__global__ void cvt_w64(const float* __restrict__ cw0, const float* __restrict__ cw1,
                        const float* __restrict__ cw2, const float* __restrict__ cw3,
                        const float* __restrict__ cw4,
                        double* __restrict__ W64, double* __restrict__ W64_5)
{
    int idx = blockIdx.x * 256 + threadIdx.x;
    const int N1 = 4 * K9 * 256, N2 = K9 * 720;
    if (idx < N1) {
        int l = idx / (K9 * 256); int rem = idx % (K9 * 256);
        int r = rem / 256, co = rem % 256;
        const float* s = l == 0 ? cw0 : l == 1 ? cw1 : l == 2 ? cw2 : cw3;
        W64[idx] = (double)s[(size_t)co * K9 + r];
        return;
    }
    idx -= N1;
    if (idx < N2) {
        int r = idx / 720, co = idx % 720;
        W64_5[idx] = (double)cw4[(size_t)co * K9 + r];
    }
}

// ---------------------------------------------------------------------------
// fp64 MFMA conv (implicit im2col GEMM). Block: 256px (16x16) x 64co, 4 waves.
// Wave: 64px x 64co = 4 Mtiles x 4 Ntiles of v_mfma_f64_16x16x4.
// LDS: li[8ci][18][20] (23.0 KB) + lb[kq][kp][co][2] (36.9 KB) = 59.9 KB.
// ---------------------------------------------------------------------------
template<typename TI, bool RELU>
__global__ __launch_bounds__(256) void conv_m64(
    const TI* __restrict__ in, const double* __restrict__ wgtT, // [K9][256]
    const float* __restrict__ bias, double* __restrict__ out,
    int H, int W)
{
    const int tilesX = (W + 15) >> 4;
    const int tx = (blockIdx.x % tilesX) * 16;
    const int ty = (blockIdx.x / tilesX) * 16;
    const int b  = blockIdx.y;
    const int co0 = blockIdx.z * 64;
    const int tid = threadIdx.x;
    const int w   = tid >> 6;
    const int lane = tid & 63;
    const int l15 = lane & 15;
    const int lq  = lane >> 4;

    __shared__ __align__(16) double li[8 * 18 * 20];
    __shared__ __align__(16) double lb[4 * 9 * 64 * 2];

    const f64x4 zero4 = {0.0, 0.0, 0.0, 0.0};
    f64x4 acc[4][4];
    #pragma unroll
    for (int mt = 0; mt < 4; ++mt)
        #pragma unroll
        for (int nt = 0; nt < 4; ++nt) acc[mt][nt] = zero4;

    int laneAoff[18];
    #pragma unroll
    for (int s = 0; s < 18; ++s) {
        int k = s * 4 + lq;
        int ci = k / 9, tap = k % 9;
        laneAoff[s] = (ci * 18 + tap / 3) * 20 + tap % 3;
    }
    int mtOff[4];
    #pragma unroll
    for (int mt = 0; mt < 4; ++mt) mtOff[mt] = (w * 4 + mt) * 20 + l15;

    for (int ch = 0; ch < 32; ++ch) {
        const int ci0 = ch * 8;
        for (int idx = tid; idx < 8 * 18 * 20; idx += 256) {
            int ci = idx / 360;
            int rr = idx % 360;
            int row = rr / 20, col = rr % 20;
            double v = 0.0;
            int iy = ty + row - 1, ix = tx + col - 1;
            if (col < 18 && iy >= 0 && iy < H && ix >= 0 && ix < W)
                v = (double)in[(((size_t)b * CIN + ci0 + ci) * H + iy) * W + ix];
            li[idx] = v;
        }
        for (int idx = tid; idx < 72 * 64; idx += 256) {
            int k = idx >> 6, co = idx & 63;
            int kq = k & 3, k4 = k >> 2;
            lb[((kq * 9 + (k4 >> 1)) * 64 + co) * 2 + (k4 & 1)] =
                wgtT[(size_t)(ci0 * 9 + k) * 256 + co0 + co];
        }
        __syncthreads();
        #pragma unroll
        for (int kp = 0; kp < 9; ++kp) {
            f64x2 bf[4];
            #pragma unroll
            for (int nt = 0; nt < 4; ++nt)
                bf[nt] = *(const f64x2*)&lb[((lq * 9 + kp) * 64 + nt * 16 + l15) * 2];
            #pragma unroll
            for (int mt = 0; mt < 4; ++mt) {
                double a0 = li[laneAoff[2 * kp]     + mtOff[mt]];
                double a1 = li[laneAoff[2 * kp + 1] + mtOff[mt]];
                #pragma unroll
                for (int nt = 0; nt < 4; ++nt) {
                    acc[mt][nt] = MFMA64(a0, bf[nt][0], acc[mt][nt]);
                    acc[mt][nt] = MFMA64(a1, bf[nt][1], acc[mt][nt]);
                }
            }
        }
        __syncthreads();
    }

    #pragma unroll
    for (int mt = 0; mt < 4; ++mt) {
        int oy = ty + w * 4 + mt;
        if (oy >= H) continue;
        #pragma unroll
        for (int nt = 0; nt < 4; ++nt) {
            int co = co0 + nt * 16 + l15;
            double bv = (double)bias[co];
            #pragma unroll
            for (int j = 0; j < 4; ++j) {
                int ox = tx + lq * 4 + j;
                if (ox < W) {
                    double v = acc[mt][nt][j] + bv;
                    if (RELU) v = v > 0.0 ? v : 0.0;
                    out[(((size_t)b * 256 + co) * H + oy) * W + ox] = v;
                }
            }
        }
    }
}

// ---------------------------------------------------------------------------
// Final cls conv (fp64 MFMA, N=80 per anchor) + fused sigmoid/max/argmax.
// Block: 16x8 px tile; wave w owns rows {2w, 2w+1}; acc[2][5]. LDS 58.9 KB.
// ---------------------------------------------------------------------------
__global__ __launch_bounds__(256) void cls5_m64(
    const double* __restrict__ in, const double* __restrict__ wgtT5, // [K9][720]
    const float* __restrict__ bias, float* __restrict__ scores,
    float* __restrict__ cls_id,
    int H, int W, int level_off, int A_total, int b0)
{
    const int tilesX = (W + 15) >> 4;
    const int tx = (blockIdx.x % tilesX) * 16;
    const int ty = (blockIdx.x / tilesX) * 8;
    const int b  = blockIdx.y;
    const int a  = blockIdx.z;
    const int tid = threadIdx.x;
    const int w   = tid >> 6;
    const int lane = tid & 63;
    const int l15 = lane & 15;
    const int lq  = lane >> 4;

    __shared__ __align__(16) double li[8 * 10 * 20];
    __shared__ __align__(16) double lb[4 * 9 * 80 * 2];

    const f64x4 zero4 = {0.0, 0.0, 0.0, 0.0};
    f64x4 acc[2][5];
    #pragma unroll
    for (int mt = 0; mt < 2; ++mt)
        #pragma unroll
        for (int nt = 0; nt < 5; ++nt) acc[mt][nt] = zero4;

    int laneAoff[18];
    #pragma unroll
    for (int s = 0; s < 18; ++s) {
        int k = s * 4 + lq;
        int ci = k / 9, tap = k % 9;
        laneAoff[s] = (ci * 10 + tap / 3) * 20 + tap % 3;
    }
    int mtOff[2];
    #pragma unroll
    for (int mt = 0; mt < 2; ++mt) mtOff[mt] = (w * 2 + mt) * 20 + l15;

    for (int ch = 0; ch < 32; ++ch) {
        const int ci0 = ch * 8;
        for (int idx = tid; idx < 8 * 10 * 20; idx += 256) {
            int ci = idx / 200;
            int rr = idx % 200;
            int row = rr / 20, col = rr % 20;
            double v = 0.0;
            int iy = ty + row - 1, ix = tx + col - 1;
            if (col < 18 && iy >= 0 && iy < H && ix >= 0 && ix < W)
                v = in[(((size_t)b * CIN + ci0 + ci) * H + iy) * W + ix];
            li[idx] = v;
        }
        for (int idx = tid; idx < 72 * 80; idx += 256) {
            int k = idx / 80, co = idx % 80;
            int kq = k & 3, k4 = k >> 2;
            lb[((kq * 9 + (k4 >> 1)) * 80 + co) * 2 + (k4 & 1)] =
                wgtT5[(size_t)(ci0 * 9 + k) * 720 + a * 80 + co];
        }
        __syncthreads();
        #pragma unroll
        for (int kp = 0; kp < 9; ++kp) {
            f64x2 bf[5];
            #pragma unroll
            for (int nt = 0; nt < 5; ++nt)
                bf[nt] = *(const f64x2*)&lb[((lq * 9 + kp) * 80 + nt * 16 + l15) * 2];
            #pragma unroll
            for (int mt = 0; mt < 2; ++mt) {
                double a0 = li[laneAoff[2 * kp]     + mtOff[mt]];
                double a1 = li[laneAoff[2 * kp + 1] + mtOff[mt]];
                #pragma unroll
                for (int nt = 0; nt < 5; ++nt) {
                    acc[mt][nt] = MFMA64(a0, bf[nt][0], acc[mt][nt]);
                    acc[mt][nt] = MFMA64(a1, bf[nt][1], acc[mt][nt]);
                }
            }
        }
        __syncthreads();
    }

    double bv[5];
    #pragma unroll
    for (int nt = 0; nt < 5; ++nt) bv[nt] = (double)bias[a * 80 + nt * 16 + l15];

    #pragma unroll
    for (int mt = 0; mt < 2; ++mt) {
        int oy = ty + w * 2 + mt;
        #pragma unroll
        for (int j = 0; j < 4; ++j) {
            double m = acc[mt][0][j] + bv[0];
            int am = l15;
            #pragma unroll
            for (int nt = 1; nt < 5; ++nt) {
                double v = acc[mt][nt][j] + bv[nt];
                if (v > m) { m = v; am = nt * 16 + l15; }
            }
            #pragma unroll
            for (int mask = 1; mask < 16; mask <<= 1) {
                double m2 = __shfl_xor(m, mask);
                int am2 = __shfl_xor(am, mask);
                if (m2 > m || (m2 == m && am2 < am)) { m = m2; am = am2; }
            }
            int ox = tx + lq * 4 + j;
            if (l15 == 0 && oy < H && ox < W) {
                size_t oi = (size_t)(b0 + b) * A_total + level_off
                          + (size_t)(oy * W + ox) * 9 + a;
                scores[oi] = (float)(1.0 / (1.0 + exp(-m)));
                cls_id[oi] = (float)am;
            }
        }
    }
}

// ---------------------------------------------------------------------------
// PROVEN round-4 vector conv (fallback cls + always the reg tower).
// ---------------------------------------------------------------------------
template<typename TI, typename TA, int CH, bool RELU>
__global__ __launch_bounds__(256, 2) void conv_tile(
    const TI* __restrict__ in, const float* __restrict__ wgt,
    const float* __restrict__ bias, TA* __restrict__ out,
    int H, int W, int C_out)
{
    const int NCH = CIN / CH;
    const int tilesX = (W + TLW - 1) / TLW;
    const int tx = (blockIdx.x % tilesX) * TLW;
    const int ty = (blockIdx.x / tilesX) * TLH;
    const int b  = blockIdx.y;
    const int co0 = blockIdx.z * 64;
    const int tid = threadIdx.x;
    const int tco = (tid >> 5) * 8;
    const int tpx = tid & 31;
    const int prow = tpx >> 2;
    const int pcol = (tpx & 3) * 4;

    __shared__ __align__(16) TA lw[CH * 9 * 64];
    __shared__ __align__(16) TA li[CH * 10 * LIS];

    TA acc[8][4];
    #pragma unroll
    for (int c = 0; c < 8; ++c)
        #pragma unroll
        for (int j = 0; j < 4; ++j) acc[c][j] = (TA)0;

    const int coLim = min(64, C_out - co0);

    for (int ch = 0; ch < NCH; ++ch) {
        const int ci0 = ch * CH;
        for (int idx = tid; idx < CH * 9 * 64; idx += 256) {
            int r  = idx >> 6;
            int co = idx & 63;
            TA v = (TA)0;
            if (co < coLim)
                v = (TA)wgt[(size_t)(co0 + co) * (CIN * 9) + (size_t)ci0 * 9 + r];
            lw[idx] = v;
        }
        for (int idx = tid; idx < CH * 10 * LIS; idx += 256) {
            int ci = idx / (10 * LIS);
            int rr = idx % (10 * LIS);
            int row = rr / LIS, col = rr % LIS;
            TA v = (TA)0;
            int iy = ty + row - 1, ix = tx + col - 1;
            if (col < TLW + 2 && iy >= 0 && iy < H && ix >= 0 && ix < W)
                v = (TA)in[(((size_t)b * CIN + ci0 + ci) * H + iy) * W + ix];
            li[idx] = v;
        }
        __syncthreads();
        #pragma unroll
        for (int ci = 0; ci < CH; ++ci) {
            #pragma unroll
            for (int ky = 0; ky < 3; ++ky) {
                const TA* ip = &li[ci * 10 * LIS + (prow + ky) * LIS + pcol];
                TA ir[6];
                #pragma unroll
                for (int t = 0; t < 6; ++t) ir[t] = ip[t];
                #pragma unroll
                for (int kx = 0; kx < 3; ++kx) {
                    const TA* wp = &lw[(ci * 9 + ky * 3 + kx) * 64 + tco];
                    TA wv[8];
                    #pragma unroll
                    for (int c = 0; c < 8; ++c) wv[c] = wp[c];
                    TA x0 = ir[kx], x1 = ir[kx + 1], x2 = ir[kx + 2], x3 = ir[kx + 3];
                    #pragma unroll
                    for (int c = 0; c < 8; ++c) {
                        acc[c][0] += wv[c] * x0;
                        acc[c][1] += wv[c] * x1;
                        acc[c][2] += wv[c] * x2;
                        acc[c][3] += wv[c] * x3;
                    }
                }
            }
        }
        __syncthreads();
    }

    const int oy = ty + prow;
    if (oy < H) {
        #pragma unroll
        for (int c = 0; c < 8; ++c) {
            int co = co0 + tco + c;
            if (co < C_out) {
                TA bv = (TA)bias[co];
                #pragma unroll
                for (int j = 0; j < 4; ++j) {
                    int ox = tx + pcol + j;
                    if (ox < W) {
                        TA v = acc[c][j] + bv;
                        if (RELU) v = v > (TA)0 ? v : (TA)0;
                        out[(((size_t)b * C_out + co) * H + oy) * W + ox] = v;
                    }
                }
            }
        }
    }
}

#define CH5 8
__global__ __launch_bounds__(256, 2) void conv_cls5(
    const double* __restrict__ in, const float* __restrict__ wgt,
    const float* __restrict__ bias, float* __restrict__ scores,
    float* __restrict__ cls_id,
    int H, int W, int level_off, int A_total, int b0)
{
    const int tilesX = (W + TLW - 1) / TLW;
    const int tx = (blockIdx.x % tilesX) * TLW;
    const int ty = (blockIdx.x / tilesX) * TLH;
    const int b  = blockIdx.y;
    const int a  = blockIdx.z;
    const int co0 = a * 80;
    const int tid = threadIdx.x;
    const int cog = tid >> 5;
    const int tco = cog * 10;
    const int tpx = tid & 31;
    const int prow = tpx >> 2;
    const int pcol = (tpx & 3) * 4;

    __shared__ __align__(16) double lw[CH5 * 9 * 80];
    __shared__ __align__(16) double li[CH5 * 10 * LIS];

    double acc[10][4];
    #pragma unroll
    for (int c = 0; c < 10; ++c)
        #pragma unroll
        for (int j = 0; j < 4; ++j) acc[c][j] = 0.0;

    for (int ch = 0; ch < CIN / CH5; ++ch) {
        const int ci0 = ch * CH5;
        for (int idx = tid; idx < CH5 * 9 * 80; idx += 256) {
            int r  = idx / 80;
            int co = idx % 80;
            lw[idx] = (double)wgt[(size_t)(co0 + co) * (CIN * 9)
                                  + (size_t)ci0 * 9 + r];
        }
        for (int idx = tid; idx < CH5 * 10 * LIS; idx += 256) {
            int ci = idx / (10 * LIS);
            int rr = idx % (10 * LIS);
            int row = rr / LIS, col = rr % LIS;
            double v = 0.0;
            int iy = ty + row - 1, ix = tx + col - 1;
            if (col < TLW + 2 && iy >= 0 && iy < H && ix >= 0 && ix < W)
                v = in[(((size_t)b * CIN + ci0 + ci) * H + iy) * W + ix];
            li[idx] = v;
        }
        __syncthreads();
        #pragma unroll
        for (int ci = 0; ci < CH5; ++ci) {
            #pragma unroll
            for (int ky = 0; ky < 3; ++ky) {
                const double* ip = &li[ci * 10 * LIS + (prow + ky) * LIS + pcol];
                double ir[6];
                #pragma unroll
                for (int t = 0; t < 6; ++t) ir[t] = ip[t];
                #pragma unroll
                for (int kx = 0; kx < 3; ++kx) {
                    const double* wp = &lw[(ci * 9 + ky * 3 + kx) * 80 + tco];
                    double wv[10];
                    #pragma unroll
                    for (int c = 0; c < 10; ++c) wv[c] = wp[c];
                    double x0 = ir[kx], x1 = ir[kx + 1], x2 = ir[kx + 2], x3 = ir[kx + 3];
                    #pragma unroll
                    for (int c = 0; c < 10; ++c) {
                        acc[c][0] += wv[c] * x0;
                        acc[c][1] += wv[c] * x1;
                        acc[c][2] += wv[c] * x2;
                        acc[c][3] += wv[c] * x3;
                    }
                }
            }
        }
        __syncthreads();
    }

    double* redM = lw;
    int*    redA = (int*)li;

    #pragma unroll
    for (int j = 0; j < 4; ++j) {
        double m = acc[0][j] + (double)bias[co0 + tco];
        int am = tco;
        #pragma unroll
        for (int c = 1; c < 10; ++c) {
            double v = acc[c][j] + (double)bias[co0 + tco + c];
            if (v > m) { m = v; am = tco + c; }
        }
        int p = prow * 16 + pcol + j;
        redM[p * 8 + cog] = m;
        redA[p * 8 + cog] = am;
    }
    __syncthreads();
    if (tid < 128) {
        int p = tid;
        double m = redM[p * 8]; int am = redA[p * 8];
        #pragma unroll
        for (int t = 1; t < 8; ++t)
            if (redM[p * 8 + t] > m) { m = redM[p * 8 + t]; am = redA[p * 8 + t]; }
        int oy = ty + (p >> 4), ox = tx + (p & 15);
        if (oy < H && ox < W) {
            size_t oi = (size_t)(b0 + b) * A_total + level_off
                      + (size_t)(oy * W + ox) * 9 + a;
            scores[oi] = (float)(1.0 / (1.0 + exp(-m)));
            cls_id[oi] = (float)am;
        }
    }
}

// ---------------------------------------------------------------------------
__global__ void boxes_ep(const float* __restrict__ reg5, float* __restrict__ boxes,
                         int H, int W, int level_off, int A_total, float stride,
                         int b0, int Bc)
{
    int idx = blockIdx.x * 256 + threadIdx.x;
    int total = Bc * H * W * 9;
    if (idx >= total) return;
    int a = idx % 9; int rest = idx / 9;
    int x = rest % W; rest /= W;
    int y = rest % H; int b = rest / H;

    float base = 4.f * stride;
    float scale = exp2f((float)(a % 3) * (1.f / 3.f));
    int ri = a / 3;
    float sr = (ri == 0) ? 0.70710678118654752f : (ri == 1 ? 1.f : 1.41421356237309505f);
    float wa = base * scale / sr;
    float ha = base * scale * sr;
    float cx = (x + 0.5f) * stride, cy = (y + 0.5f) * stride;

    size_t cs = (size_t)H * W;
    const float* rp = reg5 + (((size_t)b * 36 + a * 4) * H + y) * W + x;
    float d0 = rp[0], d1 = rp[cs], d2 = rp[2 * cs], d3 = rp[3 * cs];

    float pcx = cx + d0 * 0.1f * wa;
    float pcy = cy + d1 * 0.1f * ha;
    float pw  = expf(d2 * 0.2f) * wa;
    float ph  = expf(d3 * 0.2f) * ha;

    size_t oi = ((size_t)(b0 + b) * A_total + level_off
               + (size_t)(y * W + x) * 9 + a) * 4;
    boxes[oi + 0] = pcx - 0.5f * pw;
    boxes[oi + 1] = pcy - 0.5f * ph;
    boxes[oi + 2] = pcx + 0.5f * pw;
    boxes[oi + 3] = pcy + 0.5f * ph;
}

// ---------------------------------------------------------------------------
extern "C" void kernel_launch(void* const* d_in, const int* in_sizes, int n_in,
                              void* d_out, int out_size, void* d_ws, size_t ws_size,
                              hipStream_t stream)
{
    const float* feats[5];
    for (int i = 0; i < 5; ++i) feats[i] = (const float*)d_in[i];
    const float* cw[5]; const float* cb[5];
    const float* rw[5]; const float* rb[5];
    for (int i = 0; i < 5; ++i) {
        cw[i] = (const float*)d_in[5 + 2 * i];
        cb[i] = (const float*)d_in[6 + 2 * i];
        rw[i] = (const float*)d_in[15 + 2 * i];
        rb[i] = (const float*)d_in[16 + 2 * i];
    }

    const int A_total = 49104;
    float* scores = (float*)d_out;
    float* cls_id = scores + (size_t)8 * A_total;
    float* boxes  = scores + (size_t)2 * 8 * A_total;

    const int   Hs[5]      = {64, 32, 16, 8, 4};
    const float strides[5] = {8.f, 16.f, 32.f, 64.f, 128.f};
    const int   offs[5]    = {0, 36864, 46080, 48384, 48960};

    // ws layout: f64 transposed weights (MFMA path), then activation ping-pong
    const size_t S1 = (size_t)4 * K9 * 256 * 8;   // 18.9 MB
    const size_t S2 = (size_t)K9 * 720 * 8;       // 13.3 MB
    char* p = (char*)d_ws;
    double* W64   = (double*)p;            p += S1;
    double* W64_5 = (double*)p;            p += S2;
    size_t wsW = (size_t)(p - (char*)d_ws);
    wsW = (wsW + 255) & ~(size_t)255;
    char*  actBase  = (char*)d_ws + wsW;
    size_t actBytes = ws_size > wsW ? ws_size - wsW : 0;

    if (HAVE_MFMA64) {
        int Ntot = 4 * K9 * 256 + K9 * 720;
        cvt_w64<<<(Ntot + 255) / 256, 256, 0, stream>>>(
            cw[0], cw[1], cw[2], cw[3], cw[4], W64, W64_5);
    }

    // ---------------- cls tower (fp64) -------------------------------------
    for (int l = 0; l < 5; ++l) {
        int H = Hs[l], W = Hs[l];
        size_t perb = (size_t)CIN * H * W;
        int Bc = 8;
        while (Bc > 1 && 2ull * Bc * perb * 8 > actBytes) Bc >>= 1;
        double* D0 = (double*)actBase;
        double* D1 = D0 + (size_t)Bc * perb;
        for (int b0 = 0; b0 < 8; b0 += Bc) {
            const float* fin = feats[l] + (size_t)b0 * perb;
            if (HAVE_MFMA64) {
                int tiles16 = ((W + 15) / 16) * ((H + 15) / 16);
                int tiles5  = ((W + 15) / 16) * ((H + 7) / 8);
                dim3 g(tiles16, Bc, 4);
                conv_m64<float,  true><<<g, 256, 0, stream>>>(
                    fin, W64 + 0 * (size_t)K9 * 256, cb[0], D0, H, W);
                conv_m64<double, true><<<g, 256, 0, stream>>>(
                    D0,  W64 + 1 * (size_t)K9 * 256, cb[1], D1, H, W);
                conv_m64<double, true><<<g, 256, 0, stream>>>(
                    D1,  W64 + 2 * (size_t)K9 * 256, cb[2], D0, H, W);
                conv_m64<double, true><<<g, 256, 0, stream>>>(
                    D0,  W64 + 3 * (size_t)K9 * 256, cb[3], D1, H, W);
                dim3 g5(tiles5, Bc, 9);
                cls5_m64<<<g5, 256, 0, stream>>>(D1, W64_5, cb[4], scores, cls_id,
                                                 H, W, offs[l], A_total, b0);
            } else {
                int tiles = ((W + TLW - 1) / TLW) * ((H + TLH - 1) / TLH);
                dim3 g(tiles, Bc, 4);
                conv_tile<float,  double, 8, true><<<g, 256, 0, stream>>>(fin, cw[0], cb[0], D0, H, W, 256);
                conv_tile<double, double, 8, true><<<g, 256, 0, stream>>>(D0,  cw[1], cb[1], D1, H, W, 256);
                conv_tile<double, double, 8, true><<<g, 256, 0, stream>>>(D1,  cw[2], cb[2], D0, H, W, 256);
                conv_tile<double, double, 8, true><<<g, 256, 0, stream>>>(D0,  cw[3], cb[3], D1, H, W, 256);
                dim3 g5(tiles, Bc, 9);
                conv_cls5<<<g5, 256, 0, stream>>>(D1, cw[4], cb[4], scores, cls_id,
                                                  H, W, offs[l], A_total, b0);
            }
        }
    }

    // ---------------- reg tower (fp32, proven conv_tile) --------------------
    for (int l = 0; l < 5; ++l) {
        int H = Hs[l], W = Hs[l];
        size_t perb = (size_t)CIN * H * W;
        int Br = 8;
        while (Br > 1 && 2ull * Br * perb * 4 > actBytes) Br >>= 1;
        float* F0 = (float*)actBase;
        float* F1 = F0 + (size_t)Br * perb;
        int tiles = ((W + TLW - 1) / TLW) * ((H + TLH - 1) / TLH);
        for (int b0 = 0; b0 < 8; b0 += Br) {
            dim3 g(tiles, Br, 4);
            const float* fin = feats[l] + (size_t)b0 * perb;
            conv_tile<float, float, 8, true><<<g, 256, 0, stream>>>(fin, rw[0], rb[0], F0, H, W, 256);
            conv_tile<float, float, 8, true><<<g, 256, 0, stream>>>(F0,  rw[1], rb[1], F1, H, W, 256);
            conv_tile<float, float, 8, true><<<g, 256, 0, stream>>>(F1,  rw[2], rb[2], F0, H, W, 256);
            conv_tile<float, float, 8, true><<<g, 256, 0, stream>>>(F0,  rw[3], rb[3], F1, H, W, 256);
            dim3 gr(tiles, Br, 1);
            conv_tile<float, float, 8, false><<<gr, 256, 0, stream>>>(F1, rw[4], rb[4], F0, H, W, 36);
            int total = Br * H * W * 9;
            boxes_ep<<<(total + 255) / 256, 256, 0, stream>>>(F0, boxes, H, W,
                                                              offs[l], A_total,
                                                              strides[l], b0, Br);
        }
    }
}

// Round 11
// 24801.251 us; speedup vs baseline: 1.3503x; 1.0096x over previous
//
#include <hip/hip_runtime.h>
#include <math.h>

#define CIN 256
#define K9  2304
#define TLW 16
#define TLH 8
#define LIS 22
#define TAU 1e-3f

// ---------------------------------------------------------------------------
// PROVEN generic conv (R4/R8): 64co x (16x8)px, 256 thr, 8co x 4px per thread.
// ---------------------------------------------------------------------------
template<typename TI, typename TA, int CH, bool RELU>
__global__ __launch_bounds__(256, 2) void conv_tile(
    const TI* __restrict__ in, const float* __restrict__ wgt,
    const float* __restrict__ bias, TA* __restrict__ out,
    int H, int W, int C_out)
{
    const int NCH = CIN / CH;
    const int tilesX = (W + TLW - 1) / TLW;
    const int tx = (blockIdx.x % tilesX) * TLW;
    const int ty = (blockIdx.x / tilesX) * TLH;
    const int b  = blockIdx.y;
    const int co0 = blockIdx.z * 64;
    const int tid = threadIdx.x;
    const int tco = (tid >> 5) * 8;
    const int tpx = tid & 31;
    const int prow = tpx >> 2;
    const int pcol = (tpx & 3) * 4;

    __shared__ __align__(16) TA lw[CH * 9 * 64];
    __shared__ __align__(16) TA li[CH * 10 * LIS];

    TA acc[8][4];
    #pragma unroll
    for (int c = 0; c < 8; ++c)
        #pragma unroll
        for (int j = 0; j < 4; ++j) acc[c][j] = (TA)0;

    const int coLim = min(64, C_out - co0);

    for (int ch = 0; ch < NCH; ++ch) {
        const int ci0 = ch * CH;
        for (int idx = tid; idx < CH * 9 * 64; idx += 256) {
            int r  = idx >> 6;
            int co = idx & 63;
            TA v = (TA)0;
            if (co < coLim)
                v = (TA)wgt[(size_t)(co0 + co) * (CIN * 9) + (size_t)ci0 * 9 + r];
            lw[idx] = v;
        }
        for (int idx = tid; idx < CH * 10 * LIS; idx += 256) {
            int ci = idx / (10 * LIS);
            int rr = idx % (10 * LIS);
            int row = rr / LIS, col = rr % LIS;
            TA v = (TA)0;
            int iy = ty + row - 1, ix = tx + col - 1;
            if (col < TLW + 2 && iy >= 0 && iy < H && ix >= 0 && ix < W)
                v = (TA)in[(((size_t)b * CIN + ci0 + ci) * H + iy) * W + ix];
            li[idx] = v;
        }
        __syncthreads();
        #pragma unroll
        for (int ci = 0; ci < CH; ++ci) {
            #pragma unroll
            for (int ky = 0; ky < 3; ++ky) {
                const TA* ip = &li[ci * 10 * LIS + (prow + ky) * LIS + pcol];
                TA ir[6];
                #pragma unroll
                for (int t = 0; t < 6; ++t) ir[t] = ip[t];
                #pragma unroll
                for (int kx = 0; kx < 3; ++kx) {
                    const TA* wp = &lw[(ci * 9 + ky * 3 + kx) * 64 + tco];
                    TA wv[8];
                    #pragma unroll
                    for (int c = 0; c < 8; ++c) wv[c] = wp[c];
                    TA x0 = ir[kx], x1 = ir[kx + 1], x2 = ir[kx + 2], x3 = ir[kx + 3];
                    #pragma unroll
                    for (int c = 0; c < 8; ++c) {
                        acc[c][0] += wv[c] * x0;
                        acc[c][1] += wv[c] * x1;
                        acc[c][2] += wv[c] * x2;
                        acc[c][3] += wv[c] * x3;
                    }
                }
            }
        }
        __syncthreads();
    }

    const int oy = ty + prow;
    if (oy < H) {
        #pragma unroll
        for (int c = 0; c < 8; ++c) {
            int co = co0 + tco + c;
            if (co < C_out) {
                TA bv = (TA)bias[co];
                #pragma unroll
                for (int j = 0; j < 4; ++j) {
                    int ox = tx + pcol + j;
                    if (ox < W) {
                        TA v = acc[c][j] + bv;
                        if (RELU) v = v > (TA)0 ? v : (TA)0;
                        out[(((size_t)b * C_out + co) * H + oy) * W + ox] = v;
                    }
                }
            }
        }
    }
}

// ---------------------------------------------------------------------------
// cls5 in fp32: one anchor's 80 classes x (16x8)px; tracks max + 2nd max;
// flags ambiguous (gap < TAU) pixels. Dedicated reduction LDS (no aliasing).
// ---------------------------------------------------------------------------
#define CH5 8
__global__ __launch_bounds__(256, 2) void cls5_f32(
    const double* __restrict__ in, const float* __restrict__ wgt,
    const float* __restrict__ bias, float* __restrict__ scores,
    float* __restrict__ cls_id, unsigned char* __restrict__ flags,
    int H, int W, int level_off, int A_total, int b0)
{
    const int tilesX = (W + TLW - 1) / TLW;
    const int tx = (blockIdx.x % tilesX) * TLW;
    const int ty = (blockIdx.x / tilesX) * TLH;
    const int b  = blockIdx.y;
    const int a  = blockIdx.z;
    const int co0 = a * 80;
    const int tid = threadIdx.x;
    const int cog = tid >> 5;
    const int tco = cog * 10;
    const int tpx = tid & 31;
    const int prow = tpx >> 2;
    const int pcol = (tpx & 3) * 4;

    __shared__ __align__(16) float lw[CH5 * 9 * 80];   // 23.0 KB
    __shared__ __align__(16) float li[CH5 * 10 * LIS]; // 7.0 KB
    __shared__ float redM1[128 * 8];                   // 4 KB
    __shared__ float redM2[128 * 8];                   // 4 KB
    __shared__ int   redA [128 * 8];                   // 4 KB

    float acc[10][4];
    #pragma unroll
    for (int c = 0; c < 10; ++c)
        #pragma unroll
        for (int j = 0; j < 4; ++j) acc[c][j] = 0.f;

    for (int ch = 0; ch < CIN / CH5; ++ch) {
        const int ci0 = ch * CH5;
        for (int idx = tid; idx < CH5 * 9 * 80; idx += 256) {
            int r  = idx / 80;
            int co = idx % 80;
            lw[idx] = wgt[(size_t)(co0 + co) * (CIN * 9) + (size_t)ci0 * 9 + r];
        }
        for (int idx = tid; idx < CH5 * 10 * LIS; idx += 256) {
            int ci = idx / (10 * LIS);
            int rr = idx % (10 * LIS);
            int row = rr / LIS, col = rr % LIS;
            float v = 0.f;
            int iy = ty + row - 1, ix = tx + col - 1;
            if (col < TLW + 2 && iy >= 0 && iy < H && ix >= 0 && ix < W)
                v = (float)in[(((size_t)b * CIN + ci0 + ci) * H + iy) * W + ix];
            li[idx] = v;
        }
        __syncthreads();
        #pragma unroll
        for (int ci = 0; ci < CH5; ++ci) {
            #pragma unroll
            for (int ky = 0; ky < 3; ++ky) {
                const float* ip = &li[ci * 10 * LIS + (prow + ky) * LIS + pcol];
                float ir[6];
                #pragma unroll
                for (int t = 0; t < 6; ++t) ir[t] = ip[t];
                #pragma unroll
                for (int kx = 0; kx < 3; ++kx) {
                    const float* wp = &lw[(ci * 9 + ky * 3 + kx) * 80 + tco];
                    float wv[10];
                    #pragma unroll
                    for (int c = 0; c < 10; ++c) wv[c] = wp[c];
                    float x0 = ir[kx], x1 = ir[kx + 1], x2 = ir[kx + 2], x3 = ir[kx + 3];
                    #pragma unroll
                    for (int c = 0; c < 10; ++c) {
                        acc[c][0] = fmaf(wv[c], x0, acc[c][0]);
                        acc[c][1] = fmaf(wv[c], x1, acc[c][1]);
                        acc[c][2] = fmaf(wv[c], x2, acc[c][2]);
                        acc[c][3] = fmaf(wv[c], x3, acc[c][3]);
                    }
                }
            }
        }
        __syncthreads();
    }

    #pragma unroll
    for (int j = 0; j < 4; ++j) {
        float m1 = acc[0][j] + bias[co0 + tco];
        float m2 = -3.0e38f;
        int am = tco;
        #pragma unroll
        for (int c = 1; c < 10; ++c) {
            float v = acc[c][j] + bias[co0 + tco + c];
            if (v > m1) { m2 = m1; m1 = v; am = tco + c; }
            else if (v > m2) { m2 = v; }
        }
        int p = prow * 16 + pcol + j;
        redM1[p * 8 + cog] = m1;
        redA [p * 8 + cog] = am;
        redM2[p * 8 + cog] = m2;
    }
    __syncthreads();
    if (tid < 128) {
        int p = tid;
        float m1 = redM1[p * 8]; int am = redA[p * 8]; float m2 = redM2[p * 8];
        #pragma unroll
        for (int t = 1; t < 8; ++t) {
            float rm1 = redM1[p * 8 + t];
            float rm2 = redM2[p * 8 + t];
            if (rm1 > m1) { m2 = fmaxf(m1, rm2); m1 = rm1; am = redA[p * 8 + t]; }
            else          { m2 = fmaxf(m2, rm1); }
        }
        int oy = ty + (p >> 4), ox = tx + (p & 15);
        if (oy < H && ox < W) {
            size_t oi = (size_t)(b0 + b) * A_total + level_off
                      + (size_t)(oy * W + ox) * 9 + a;
            scores[oi] = 1.f / (1.f + expf(-m1));
            cls_id[oi] = (float)am;
            flags[((size_t)b * H * W + oy * W + ox) * 9 + a] =
                (m1 - m2 < TAU) ? 1 : 0;
        }
    }
}

// ---------------------------------------------------------------------------
// fp64 fixup for flagged (px, anchor): exact 80-logit recompute from fp64 D1.
// No early return; body guarded by the block-uniform flag.
// ---------------------------------------------------------------------------
__global__ __launch_bounds__(128) void fixup_cls(
    const double* __restrict__ in, const float* __restrict__ wgt,
    const float* __restrict__ bias, const unsigned char* __restrict__ flags,
    float* __restrict__ scores, float* __restrict__ cls_id,
    int H, int W, int level_off, int A_total, int b0)
{
    const int px = blockIdx.x;
    const int b  = blockIdx.y;
    const int a  = blockIdx.z;
    const int tid = threadIdx.x;
    const unsigned char fl = flags[((size_t)b * H * W + px) * 9 + a];

    __shared__ double patch[K9];
    __shared__ double lg[80];

    if (fl) {
        const int y = px / W, x = px % W;
        for (int idx = tid; idx < K9; idx += 128) {
            int ci = idx / 9, tap = idx % 9;
            int iy = y + tap / 3 - 1, ix = x + tap % 3 - 1;
            double v = 0.0;
            if (iy >= 0 && iy < H && ix >= 0 && ix < W)
                v = in[(((size_t)b * CIN + ci) * H + iy) * W + ix];
            patch[idx] = v;
        }
        __syncthreads();
        if (tid < 80) {
            const float* wr = wgt + (size_t)(a * 80 + tid) * K9;
            double s = 0.0;
            for (int k = 0; k < K9; ++k) s += (double)wr[k] * patch[k];
            lg[tid] = s + (double)bias[a * 80 + tid];
        }
        __syncthreads();
        if (tid == 0) {
            double m = lg[0]; int am = 0;
            for (int c = 1; c < 80; ++c)
                if (lg[c] > m) { m = lg[c]; am = c; }
            size_t oi = (size_t)(b0 + b) * A_total + level_off + (size_t)px * 9 + a;
            scores[oi] = (float)(1.0 / (1.0 + exp(-m)));
            cls_id[oi] = (float)am;
        }
    }
}

// ---------------------------------------------------------------------------
__global__ void boxes_ep(const float* __restrict__ reg5, float* __restrict__ boxes,
                         int H, int W, int level_off, int A_total, float stride,
                         int b0, int Bc)
{
    int idx = blockIdx.x * 256 + threadIdx.x;
    int total = Bc * H * W * 9;
    if (idx >= total) return;
    int a = idx % 9; int rest = idx / 9;
    int x = rest % W; rest /= W;
    int y = rest % H; int b = rest / H;

    float base = 4.f * stride;
    float scale = exp2f((float)(a % 3) * (1.f / 3.f));
    int ri = a / 3;
    float sr = (ri == 0) ? 0.70710678118654752f : (ri == 1 ? 1.f : 1.41421356237309505f);
    float wa = base * scale / sr;
    float ha = base * scale * sr;
    float cx = (x + 0.5f) * stride, cy = (y + 0.5f) * stride;

    size_t cs = (size_t)H * W;
    const float* rp = reg5 + (((size_t)b * 36 + a * 4) * H + y) * W + x;
    float d0 = rp[0], d1 = rp[cs], d2 = rp[2 * cs], d3 = rp[3 * cs];

    float pcx = cx + d0 * 0.1f * wa;
    float pcy = cy + d1 * 0.1f * ha;
    float pw  = expf(d2 * 0.2f) * wa;
    float ph  = expf(d3 * 0.2f) * ha;

    size_t oi = ((size_t)(b0 + b) * A_total + level_off
               + (size_t)(y * W + x) * 9 + a) * 4;
    boxes[oi + 0] = pcx - 0.5f * pw;
    boxes[oi + 1] = pcy - 0.5f * ph;
    boxes[oi + 2] = pcx + 0.5f * pw;
    boxes[oi + 3] = pcy + 0.5f * ph;
}

// ---------------------------------------------------------------------------
extern "C" void kernel_launch(void* const* d_in, const int* in_sizes, int n_in,
                              void* d_out, int out_size, void* d_ws, size_t ws_size,
                              hipStream_t stream)
{
    const float* feats[5];
    for (int i = 0; i < 5; ++i) feats[i] = (const float*)d_in[i];
    const float* cw[5]; const float* cb[5];
    const float* rw[5]; const float* rb[5];
    for (int i = 0; i < 5; ++i) {
        cw[i] = (const float*)d_in[5 + 2 * i];
        cb[i] = (const float*)d_in[6 + 2 * i];
        rw[i] = (const float*)d_in[15 + 2 * i];
        rb[i] = (const float*)d_in[16 + 2 * i];
    }

    const int A_total = 49104;
    float* scores = (float*)d_out;
    float* cls_id = scores + (size_t)8 * A_total;
    float* boxes  = scores + (size_t)2 * 8 * A_total;

    const int   Hs[5]      = {64, 32, 16, 8, 4};
    const float strides[5] = {8.f, 16.f, 32.f, 64.f, 128.f};
    const int   offs[5]    = {0, 36864, 46080, 48384, 48960};

    // ws: [128 KB flags][activation ping-pong ......]
    const size_t flagRes = 131072;
    unsigned char* flags = (unsigned char*)d_ws;
    char*  actBase  = (char*)d_ws + flagRes;
    size_t actBytes = ws_size > flagRes ? ws_size - flagRes : 0;

    // ---------------- cls tower (fp64 conv + fp32 cls5 + fp64 fixup) -------
    for (int l = 0; l < 5; ++l) {
        int H = Hs[l], W = Hs[l];
        size_t perb = (size_t)CIN * H * W;
        int Bc = 8;
        while (Bc > 1 && 2ull * Bc * perb * 8 > actBytes) Bc >>= 1;
        double* D0 = (double*)actBase;
        double* D1 = D0 + (size_t)Bc * perb;
        int tiles = ((W + TLW - 1) / TLW) * ((H + TLH - 1) / TLH);
        for (int b0 = 0; b0 < 8; b0 += Bc) {
            const float* fin = feats[l] + (size_t)b0 * perb;
            dim3 g(tiles, Bc, 4);
            conv_tile<float,  double, 8, true><<<g, 256, 0, stream>>>(fin, cw[0], cb[0], D0, H, W, 256);
            conv_tile<double, double, 8, true><<<g, 256, 0, stream>>>(D0,  cw[1], cb[1], D1, H, W, 256);
            conv_tile<double, double, 8, true><<<g, 256, 0, stream>>>(D1,  cw[2], cb[2], D0, H, W, 256);
            conv_tile<double, double, 8, true><<<g, 256, 0, stream>>>(D0,  cw[3], cb[3], D1, H, W, 256);
            dim3 g5(tiles, Bc, 9);
            cls5_f32<<<g5, 256, 0, stream>>>(D1, cw[4], cb[4], scores, cls_id,
                                             flags, H, W, offs[l], A_total, b0);
            dim3 gf(H * W, Bc, 9);
            fixup_cls<<<gf, 128, 0, stream>>>(D1, cw[4], cb[4], flags,
                                              scores, cls_id,
                                              H, W, offs[l], A_total, b0);
        }
    }

    // ---------------- reg tower (fp32, proven) ------------------------------
    for (int l = 0; l < 5; ++l) {
        int H = Hs[l], W = Hs[l];
        size_t perb = (size_t)CIN * H * W;
        int Br = 8;
        while (Br > 1 && 2ull * Br * perb * 4 > actBytes) Br >>= 1;
        float* F0 = (float*)actBase;
        float* F1 = F0 + (size_t)Br * perb;
        int tiles = ((W + TLW - 1) / TLW) * ((H + TLH - 1) / TLH);
        for (int b0 = 0; b0 < 8; b0 += Br) {
            dim3 g(tiles, Br, 4);
            const float* fin = feats[l] + (size_t)b0 * perb;
            conv_tile<float, float, 8, true><<<g, 256, 0, stream>>>(fin, rw[0], rb[0], F0, H, W, 256);
            conv_tile<float, float, 8, true><<<g, 256, 0, stream>>>(F0,  rw[1], rb[1], F1, H, W, 256);
            conv_tile<float, float, 8, true><<<g, 256, 0, stream>>>(F1,  rw[2], rb[2], F0, H, W, 256);
            conv_tile<float, float, 8, true><<<g, 256, 0, stream>>>(F0,  rw[3], rb[3], F1, H, W, 256);
            dim3 gr(tiles, Br, 1);
            conv_tile<float, float, 8, false><<<gr, 256, 0, stream>>>(F1, rw[4], rb[4], F0, H, W, 36);
            int total = Br * H * W * 9;
            boxes_ep<<<(total + 255) / 256, 256, 0, stream>>>(F0, boxes, H, W,
                                                              offs[l], A_total,
                                                              strides[l], b0, Br);
        }
    }
}